// Round 1
// baseline (5313.263 us; speedup 1.0000x reference)
//
#include <hip/hip_runtime.h>
#include <math.h>

#define NPATHS 65536
#define NSTEPS 512

// gelu(x) approx (JAX approximate=True), via sigmoid identity:
// 0.5*x*(1+tanh(c*(x+0.044715 x^3))) == x * sigmoid(2c*x*(1+0.044715 x^2))
__device__ __forceinline__ float gelu_fast(float x) {
    float x2 = x * x;
    float u = 1.5957691216057308f * x * fmaf(0.044715f, x2, 1.0f);
    float e = __expf(-u);                       // e^{-u}
    return x * __builtin_amdgcn_rcpf(1.0f + e); // x * sigmoid(u)
}

extern "C" __global__ void __launch_bounds__(256, 1)
sde_kernel(const float* __restrict__ z1, const float* __restrict__ z2,
           const float* __restrict__ W1, const float* __restrict__ b1,
           const float* __restrict__ W2, const float* __restrict__ b2,
           const float* __restrict__ W3, const float* __restrict__ b3,
           const float* __restrict__ init_log_v,
           float* __restrict__ out)
{
    __shared__ float sW1[64];
    __shared__ float sb1[32];
    __shared__ float sW2[1024];
    __shared__ float sb2[32];
    __shared__ float sW3[32];
    __shared__ float sb3[1];

    const int tid = threadIdx.x;
    for (int i = tid; i < 1024; i += 256) sW2[i] = W2[i];
    if (tid < 64) sW1[tid] = W1[tid];
    if (tid < 32) { sb1[tid] = b1[tid]; sb2[tid] = b2[tid]; sW3[tid] = W3[tid]; }
    if (tid == 0) sb3[0] = b3[0];
    __syncthreads();

    const int p = blockIdx.x * 256 + tid;

    const float DTf = 1.0f / 252.0f;            // f32(1/252)
    const float sqrt_dt = sqrtf(DTf);           // matches jnp.sqrt(f32(DT))
    const float c_dws2 = sqrtf(0.2775f) * sqrt_dt; // f32(sqrt(f32(0.2775))) * sqrt_dt

    float log_v = init_log_v[0];
    float log_s = 0.0f;
    float lam_sq = 0.0f;

    const float* z1p = z1 + (size_t)p * NSTEPS;
    const float* z2p = z2 + (size_t)p * NSTEPS;
    float* out_lv = out + (size_t)p * NSTEPS;
    float* out_sp = out + (size_t)NPATHS * NSTEPS + (size_t)p * NSTEPS;
    float* out_lamsq = out + (size_t)NPATHS * NSTEPS * 2;

    for (int n = 0; n < NSTEPS; ++n) {
        float z1e = z1p[n];
        float z2e = z2p[n];

        // t_idx[n] = (f32(n) * f32(DT)) / f32(512*DT)
        float tn = ((float)n * DTf) / 2.0317460317460316f;

        float dwv = sqrt_dt * z1e;
        float dws = (-0.85f) * dwv + c_dws2 * z2e;

        // ---- MLP(2->32->32->1), gelu, tanh-bounded ----
        float h1[32];
        #pragma unroll
        for (int j = 0; j < 32; ++j) {
            float pre = fmaf(sW1[2*j], log_v, fmaf(sW1[2*j+1], tn, sb1[j]));
            h1[j] = gelu_fast(pre);
        }
        float raw = sb3[0];
        #pragma unroll
        for (int j = 0; j < 32; ++j) {
            float acc = sb2[j];
            #pragma unroll
            for (int i = 0; i < 32; ++i)
                acc = fmaf(h1[i], sW2[32*j + i], acc);
            raw = fmaf(gelu_fast(acc), sW3[j], raw);
        }
        // lam = 3 * tanh(raw);  tanh(r) = 1 - 2/(1+e^{2r}) (safe at both tails)
        float e2 = __expf(2.0f * raw);
        float lam = 3.0f * (1.0f - 2.0f * __builtin_amdgcn_rcpf(1.0f + e2));

        // ---- SDE step ----
        float mu_p = (2.72f * (-3.5f - log_v)) * DTf;
        float drift_q = mu_p - (lam * 0.85f) * DTf;
        float lvn = log_v + drift_q + 0.85f * dwv;
        lvn = fminf(fmaxf(lvn, -7.0f), 2.0f);

        float ev = expf(log_v);                  // uses pre-update log_v
        float vol = sqrtf(fmaxf(ev, 1e-10f));
        float lsn = log_s + (0.0373f - 0.5f * ev) * DTf + vol * dws;

        lam_sq = lam_sq + (lam * lam) * DTf;

        log_v = lvn;
        log_s = lsn;

        out_lv[n] = lvn;
        out_sp[n] = expf(lsn);
    }
    out_lamsq[p] = lam_sq;
}

extern "C" void kernel_launch(void* const* d_in, const int* in_sizes, int n_in,
                              void* d_out, int out_size, void* d_ws, size_t ws_size,
                              hipStream_t stream) {
    const float* z1  = (const float*)d_in[0];
    const float* z2  = (const float*)d_in[1];
    const float* W1  = (const float*)d_in[2];
    const float* b1  = (const float*)d_in[3];
    const float* W2  = (const float*)d_in[4];
    const float* b2  = (const float*)d_in[5];
    const float* W3  = (const float*)d_in[6];
    const float* b3  = (const float*)d_in[7];
    const float* ilv = (const float*)d_in[8];

    dim3 grid(NPATHS / 256);
    dim3 block(256);
    hipLaunchKernelGGL(sde_kernel, grid, block, 0, stream,
                       z1, z2, W1, b1, W2, b2, W3, b3, ilv, (float*)d_out);
}

// Round 2
// 5292.789 us; speedup vs baseline: 1.0039x; 1.0039x over previous
//
#include <hip/hip_runtime.h>
#include <math.h>

#define NPATHS 65536
#define NSTEPS 512
#define T 4   // steps per I/O tile: 16B float4 loads/stores per array

// gelu(x) approx (JAX approximate=True), via sigmoid identity:
// 0.5*x*(1+tanh(c*(x+0.044715 x^3))) == x * sigmoid(2c*x*(1+0.044715 x^2))
__device__ __forceinline__ float gelu_fast(float x) {
    float x2 = x * x;
    float u = 1.5957691216057308f * x * fmaf(0.044715f, x2, 1.0f);
    float e = __expf(-u);                       // e^{-u}
    return x * __builtin_amdgcn_rcpf(1.0f + e); // x * sigmoid(u)
}

extern "C" __global__ void __launch_bounds__(256, 1)
sde_kernel(const float* __restrict__ z1, const float* __restrict__ z2,
           const float* __restrict__ W1, const float* __restrict__ b1,
           const float* __restrict__ W2, const float* __restrict__ b2,
           const float* __restrict__ W3, const float* __restrict__ b3,
           const float* __restrict__ init_log_v,
           float* __restrict__ out)
{
    // W2 rows as float4 -> ds_read_b128 broadcast (4 weights / LDS op, was 1)
    __shared__ float4 sW2v[256];   // sW2v[j*8+q] = W2[j][4q..4q+3]
    __shared__ float2 sW1v[32];
    __shared__ float  sb1[32], sb2[32], sW3[32];
    __shared__ float  sb3;

    const int tid = threadIdx.x;
    sW2v[tid] = ((const float4*)W2)[tid];              // 256 threads, 256 float4
    if (tid < 32) {
        sW1v[tid] = ((const float2*)W1)[tid];
        sb1[tid] = b1[tid]; sb2[tid] = b2[tid]; sW3[tid] = W3[tid];
    }
    if (tid == 0) sb3 = b3[0];
    __syncthreads();

    const int p = blockIdx.x * 256 + tid;

    const float DTf = 1.0f / 252.0f;
    const float sqrt_dt = sqrtf(DTf);                  // matches jnp.sqrt(f32(DT))
    const float c_dws2 = sqrtf(0.2775f) * sqrt_dt;

    float log_v = init_log_v[0];
    float log_s = 0.0f;
    float lam_sq = 0.0f;

    const float4* z1p = (const float4*)(z1 + (size_t)p * NSTEPS);
    const float4* z2p = (const float4*)(z2 + (size_t)p * NSTEPS);
    float4* out_lv = (float4*)(out + (size_t)p * NSTEPS);
    float4* out_sp = (float4*)(out + (size_t)NPATHS * NSTEPS + (size_t)p * NSTEPS);
    float* out_lamsq = out + (size_t)NPATHS * NSTEPS * 2;

    // One simulation step. Arithmetic order kept bit-identical to the
    // passing round-1 baseline (acc sequential i=0..31 per row; raw
    // sequential j=0..31; same expf/__expf choices).
    auto step = [&](int n, float z1e, float z2e, float& lvout, float& spout) {
        float tn = ((float)n * DTf) / 2.0317460317460316f;

        float dwv = sqrt_dt * z1e;
        float dws = (-0.85f) * dwv + c_dws2 * z2e;

        // ---- MLP(2->32->32->1), gelu, tanh-bounded ----
        float h1[32];
        #pragma unroll
        for (int j = 0; j < 32; ++j) {
            float2 w = sW1v[j];
            h1[j] = gelu_fast(fmaf(w.x, log_v, fmaf(w.y, tn, sb1[j])));
        }
        float raw = sb3;
        // unroll 4: four independent acc chains in flight (ILP for the
        // single resident wave/SIMD) while preserving j order for raw.
        #pragma unroll 4
        for (int j = 0; j < 32; ++j) {
            float acc = sb2[j];
            #pragma unroll
            for (int q = 0; q < 8; ++q) {
                float4 w = sW2v[j * 8 + q];          // one ds_read_b128
                acc = fmaf(h1[4*q + 0], w.x, acc);
                acc = fmaf(h1[4*q + 1], w.y, acc);
                acc = fmaf(h1[4*q + 2], w.z, acc);
                acc = fmaf(h1[4*q + 3], w.w, acc);
            }
            raw = fmaf(gelu_fast(acc), sW3[j], raw);
        }
        // lam = 3 * tanh(raw);  tanh(r) = 1 - 2/(1+e^{2r})
        float e2 = __expf(2.0f * raw);
        float lam = 3.0f * (1.0f - 2.0f * __builtin_amdgcn_rcpf(1.0f + e2));

        // ---- SDE step ----
        float mu_p = (2.72f * (-3.5f - log_v)) * DTf;
        float drift_q = mu_p - (lam * 0.85f) * DTf;
        float lvn = log_v + drift_q + 0.85f * dwv;
        lvn = fminf(fmaxf(lvn, -7.0f), 2.0f);

        float ev = expf(log_v);                      // pre-update log_v
        float vol = sqrtf(fmaxf(ev, 1e-10f));
        float lsn = log_s + (0.0373f - 0.5f * ev) * DTf + vol * dws;

        lam_sq = lam_sq + (lam * lam) * DTf;

        log_v = lvn;
        log_s = lsn;

        lvout = lvn;
        spout = expf(lsn);
    };

    for (int n0 = 0; n0 < NSTEPS; n0 += T) {
        // 16B/lane coalesced tile loads (full-line use, kills read overfetch)
        float4 za = z1p[n0 / 4];
        float4 zb = z2p[n0 / 4];

        float4 lvb, spb;
        step(n0 + 0, za.x, zb.x, lvb.x, spb.x);
        step(n0 + 1, za.y, zb.y, lvb.y, spb.y);
        step(n0 + 2, za.z, zb.z, lvb.z, spb.z);
        step(n0 + 3, za.w, zb.w, lvb.w, spb.w);

        // 16B/lane buffered stores (kills the 16x write amplification)
        out_lv[n0 / 4] = lvb;
        out_sp[n0 / 4] = spb;
    }
    out_lamsq[p] = lam_sq;
}

extern "C" void kernel_launch(void* const* d_in, const int* in_sizes, int n_in,
                              void* d_out, int out_size, void* d_ws, size_t ws_size,
                              hipStream_t stream) {
    const float* z1  = (const float*)d_in[0];
    const float* z2  = (const float*)d_in[1];
    const float* W1  = (const float*)d_in[2];
    const float* b1  = (const float*)d_in[3];
    const float* W2  = (const float*)d_in[4];
    const float* b2  = (const float*)d_in[5];
    const float* W3  = (const float*)d_in[6];
    const float* b3  = (const float*)d_in[7];
    const float* ilv = (const float*)d_in[8];

    dim3 grid(NPATHS / 256);
    dim3 block(256);
    hipLaunchKernelGGL(sde_kernel, grid, block, 0, stream,
                       z1, z2, W1, b1, W2, b2, W3, b3, ilv, (float*)d_out);
}